// Round 1
// baseline (165.513 us; speedup 1.0000x reference)
//
#include <hip/hip_runtime.h>

#define NN 50000
#define NE 800000
#define DD 128
#define TILE_M 64
#define CAP 64            // per-node slot capacity; deg ~ Poisson(16), P(>64) ~ 1e-20

#define NBG ((NN + TILE_M - 1) / TILE_M)   // 782 gemm blocks
#define ECHUNK 2048                        // edges scanned per scatter-block-octet
#define NCH ((NE + ECHUNK - 1) / ECHUNK)   // 391 chunks
#define NBS (NCH * 8)                      // 3128 scatter blocks (8 residues/chunk)

typedef __attribute__((ext_vector_type(8))) short short8;
typedef __attribute__((ext_vector_type(4))) float f32x4;

__device__ __forceinline__ unsigned short f2bf(float f) {
    unsigned int u = __float_as_uint(f);
    u += 0x7fffu + ((u >> 16) & 1u);   // RNE
    return (unsigned short)(u >> 16);
}

// ---------------- prologue: zero deg + W fp32->bf16 (replaces memset) --------
__global__ __launch_bounds__(256) void prologue(
    const float* __restrict__ W, unsigned short* __restrict__ Wbf,
    int* __restrict__ deg)
{
    const int t = blockIdx.x * 256 + threadIdx.x;
    for (int i = t; i < NN; i += 64 * 256) deg[i] = 0;
    if (blockIdx.x == 0) {
        for (int i = threadIdx.x; i < 128 * 32; i += 256) {
            const float4 w4 = ((const float4*)W)[i];
            ushort4 s4;
            s4.x = f2bf(w4.x); s4.y = f2bf(w4.y);
            s4.z = f2bf(w4.z); s4.w = f2bf(w4.w);
            *(ushort4*)(Wbf + i * 4) = s4;
        }
    }
}

// ---------------- Fused: GEMM tiles + XCD-local edge placement ----------------
// Blocks [0,NBG): h = x@W^T + b -> out (fp32) and hbf (bf16).
//   ZERO LDS: A-fragments read per-lane from x (each element exactly once per
//   block, fp32->bf16 in reg); B-fragments short8-loaded from bf16 W in
//   workspace (32 KB, L2-resident). Removing the 52 KB static LDS lifts the
//   residency cap from 3 blocks/CU to the wave/VGPR limit (~6 waves/EU), which
//   is what the latency-bound scatter blocks need.
// Blocks [NBG,NBG+NBS): 8 consecutive blocks share one 2048-edge chunk; block
// with (blockIdx&7)==p keeps only rows with (r&7)==p. Consecutive blockIdx
// round-robin across XCDs (heuristic), so all writes to a given node's
// deg/slots lines issue from ONE XCD -> no cross-XCD line migration.
// Correct regardless of the mapping: each (chunk, residue) covered once.
__global__ __launch_bounds__(256, 6) void fused_gemm_scatter(
    const float* __restrict__ x, const unsigned short* __restrict__ Wbf,
    const float* __restrict__ b, const int* __restrict__ ei,
    float* __restrict__ out, unsigned short* __restrict__ hbf,
    int* __restrict__ deg, int* __restrict__ slots)
{
    if (blockIdx.x >= NBG) {
        const int part  = blockIdx.x & 7;                 // aligns with XCD round-robin
        const int chunk = (blockIdx.x - NBG) >> 3;
        const int base  = chunk * ECHUNK;
#pragma unroll
        for (int i = 0; i < 8; ++i) {
            const int e = base + i * 256 + threadIdx.x;
            if (e < NE) {
                const int r = ei[e];
                if ((r & 7) == part) {
                    const int c = ei[NE + e];
                    const int p = atomicAdd(&deg[r], 1);
                    if (p < CAP) slots[r * CAP + p] = c;
                }
            }
        }
        return;
    }

    const int t    = threadIdx.x;
    const int lane = t & 63;
    const int wave = t >> 6;
    const int m16  = lane & 15;
    const int quad = lane >> 4;

    const int row0 = blockIdx.x * TILE_M;
    int gr = row0 + wave * 16 + m16;
    if (gr > NN - 1) gr = NN - 1;          // clamped rows never stored

    // A fragments straight from global x (row gr, cols kc*32+quad*8 .. +7)
    short8 afrag[4];
#pragma unroll
    for (int kc = 0; kc < 4; ++kc) {
        const float4 a0 = *(const float4*)(x + (size_t)gr * 128 + kc * 32 + quad * 8);
        const float4 a1 = *(const float4*)(x + (size_t)gr * 128 + kc * 32 + quad * 8 + 4);
        short8 af;
        af[0] = (short)f2bf(a0.x); af[1] = (short)f2bf(a0.y);
        af[2] = (short)f2bf(a0.z); af[3] = (short)f2bf(a0.w);
        af[4] = (short)f2bf(a1.x); af[5] = (short)f2bf(a1.y);
        af[6] = (short)f2bf(a1.z); af[7] = (short)f2bf(a1.w);
        afrag[kc] = af;
    }

    f32x4 acc[8];
#pragma unroll
    for (int nt = 0; nt < 8; ++nt) acc[nt] = (f32x4){0.f, 0.f, 0.f, 0.f};

#pragma unroll
    for (int kc = 0; kc < 4; ++kc) {
#pragma unroll
        for (int nt = 0; nt < 8; ++nt) {
            const short8 bfrag =
                *(const short8*)(Wbf + (nt * 16 + m16) * 128 + kc * 32 + quad * 8);
            acc[nt] = __builtin_amdgcn_mfma_f32_16x16x32_bf16(
                afrag[kc], bfrag, acc[nt], 0, 0, 0);
        }
    }

    const int rbase = row0 + wave * 16 + quad * 4;
#pragma unroll
    for (int nt = 0; nt < 8; ++nt) {
        const float bias = b[nt * 16 + m16];
#pragma unroll
        for (int r = 0; r < 4; ++r) {
            const int grow = rbase + r;
            if (grow < NN) {
                const float v = acc[nt][r] + bias;
                out[(size_t)grow * 128 + nt * 16 + m16] = v;   // residual base
                hbf[(size_t)grow * 128 + nt * 16 + m16] = f2bf(v);
            }
        }
    }
}

// ---------------- agg: out[n] += sum_{k<deg[n]} h[slots[n][k]] ------------
// One wave per node. Lane = (g,s): g=lane>>4 picks one of 4 concurrent
// edges, s=lane&15 owns 8 cols (16 B uint4 gather). 16 edges/round, 4
// exec-masked loads in flight. Cross-group reduce: 2 shfl_xor steps.
__global__ __launch_bounds__(256) void agg_kernel(
    const int* __restrict__ deg, const int* __restrict__ slots,
    const unsigned short* __restrict__ hbf, float* __restrict__ out)
{
    const int n = (blockIdx.x * 256 + threadIdx.x) >> 6;   // wave-uniform
    if (n >= NN) return;
    const int lane = threadIdx.x & 63;
    const int g = lane >> 4;       // edge group 0..3
    const int s = lane & 15;       // col sub-lane: cols s*8 .. s*8+7

    const int dn_raw = deg[n];
    const int idx    = slots[n * CAP + lane];
    float4 r0, r1;
    if (g == 0) {
        r0 = *(const float4*)(out + (size_t)n * 128 + s * 8);
        r1 = *(const float4*)(out + (size_t)n * 128 + s * 8 + 4);
    }
    const int dn = min(dn_raw, CAP);

    float acc[8];
#pragma unroll
    for (int i = 0; i < 8; ++i) acc[i] = 0.f;

    for (int k = 0; k < dn; k += 16) {
        uint4 p[4];
#pragma unroll
        for (int bb = 0; bb < 4; ++bb) {
            const int e = k + bb * 4 + g;
            const int c = __shfl(idx, e, 64);
            p[bb] = (uint4){0u, 0u, 0u, 0u};
            if (e < dn)
                p[bb] = *(const uint4*)(hbf + (size_t)c * 128 + s * 8);
        }
#pragma unroll
        for (int bb = 0; bb < 4; ++bb) {
            acc[0] += __uint_as_float(p[bb].x << 16);
            acc[1] += __uint_as_float(p[bb].x & 0xffff0000u);
            acc[2] += __uint_as_float(p[bb].y << 16);
            acc[3] += __uint_as_float(p[bb].y & 0xffff0000u);
            acc[4] += __uint_as_float(p[bb].z << 16);
            acc[5] += __uint_as_float(p[bb].z & 0xffff0000u);
            acc[6] += __uint_as_float(p[bb].w << 16);
            acc[7] += __uint_as_float(p[bb].w & 0xffff0000u);
        }
    }

#pragma unroll
    for (int i = 0; i < 8; ++i) acc[i] += __shfl_xor(acc[i], 16, 64);
#pragma unroll
    for (int i = 0; i < 8; ++i) acc[i] += __shfl_xor(acc[i], 32, 64);

    if (g == 0) {
        r0.x += acc[0]; r0.y += acc[1]; r0.z += acc[2]; r0.w += acc[3];
        r1.x += acc[4]; r1.y += acc[5]; r1.z += acc[6]; r1.w += acc[7];
        *(float4*)(out + (size_t)n * 128 + s * 8)     = r0;
        *(float4*)(out + (size_t)n * 128 + s * 8 + 4) = r1;
    }
}

extern "C" void kernel_launch(void* const* d_in, const int* in_sizes, int n_in,
                              void* d_out, int out_size, void* d_ws, size_t ws_size,
                              hipStream_t stream)
{
    const float* x  = (const float*)d_in[0];
    const int*   ei = (const int*)d_in[1];   // int32
    const float* W  = (const float*)d_in[2];
    const float* b  = (const float*)d_in[3];
    float* out = (float*)d_out;

    // Workspace (~25.9 MB): hbf | slots | deg | Wbf
    unsigned short* hbf   = (unsigned short*)d_ws;                // NN*DD bf16
    int*            slots = (int*)(hbf + (size_t)NN * DD);        // NN*CAP
    int*            deg   = slots + (size_t)NN * CAP;             // NN
    unsigned short* Wbf   = (unsigned short*)(deg + NN);          // 128*128 bf16

    prologue<<<64, 256, 0, stream>>>(W, Wbf, deg);

    fused_gemm_scatter<<<NBG + NBS, 256, 0, stream>>>(x, Wbf, b, ei, out, hbf, deg, slots);

    agg_kernel<<<(NN * 64 + 255) / 256, 256, 0, stream>>>(deg, slots, hbf, out);
}

// Round 2
// 163.627 us; speedup vs baseline: 1.0115x; 1.0115x over previous
//
#include <hip/hip_runtime.h>

#define NN 50000
#define NE 800000
#define DD 128
#define TILE_M 64
#define CAP 64            // per-node slot capacity; deg ~ Poisson(16), P(>64) ~ 1e-20

#define NBG ((NN + TILE_M - 1) / TILE_M)   // 782 gemm blocks
#define ECHUNK 2048                        // edges scanned per scatter-block-octet
#define NCH ((NE + ECHUNK - 1) / ECHUNK)   // 391 chunks
#define NBS (NCH * 8)                      // 3128 scatter blocks (8 residues/chunk)

typedef __attribute__((ext_vector_type(8))) short short8;
typedef __attribute__((ext_vector_type(4))) float f32x4;

__device__ __forceinline__ unsigned short f2bf(float f) {
    unsigned int u = __float_as_uint(f);
    u += 0x7fffu + ((u >> 16) & 1u);   // RNE
    return (unsigned short)(u >> 16);
}

// ---------------- prologue: zero deg + W fp32->bf16 (replaces memset) --------
__global__ __launch_bounds__(256) void prologue(
    const float* __restrict__ W, unsigned short* __restrict__ Wbf,
    int* __restrict__ deg)
{
    const int t = blockIdx.x * 256 + threadIdx.x;
    for (int i = t; i < NN; i += 64 * 256) deg[i] = 0;
    if (blockIdx.x == 0) {
        for (int i = threadIdx.x; i < 128 * 32; i += 256) {
            const float4 w4 = ((const float4*)W)[i];
            ushort4 s4;
            s4.x = f2bf(w4.x); s4.y = f2bf(w4.y);
            s4.z = f2bf(w4.z); s4.w = f2bf(w4.w);
            *(ushort4*)(Wbf + i * 4) = s4;
        }
    }
}

// ---------------- Fused: GEMM tiles + XCD-line-local edge placement ----------
// Blocks [0,NBG): h = x@W^T + b -> out (fp32) and hbf (bf16). ZERO LDS.
// Blocks [NBG,NBG+NBS): 8 consecutive blocks share one 2048-edge chunk; block
// with (blockIdx&7)==p keeps only rows whose deg CACHE LINE belongs to class
// p: ((r>>4)&7)==p. A 64B deg line holds 16 consecutive nodes; partitioning by
// (r&7) (previous version) let all 8 XCD classes hammer every line -> line
// migration between non-coherent L2s serialized ~256 atomics/line at remote
// latency (occupancy-independent ~70us floor). Line-granular partitioning
// keeps each deg line (and each 256B slots row) written by ONE class only.
// Correct regardless of the blockIdx->XCD mapping: each (chunk, class) pair
// is covered exactly once.
__global__ __launch_bounds__(256, 6) void fused_gemm_scatter(
    const float* __restrict__ x, const unsigned short* __restrict__ Wbf,
    const float* __restrict__ b, const int* __restrict__ ei,
    float* __restrict__ out, unsigned short* __restrict__ hbf,
    int* __restrict__ deg, int* __restrict__ slots)
{
    if (blockIdx.x >= NBG) {
        const int part  = blockIdx.x & 7;                 // aligns with XCD round-robin
        const int chunk = (blockIdx.x - NBG) >> 3;
        const int base  = chunk * ECHUNK;
#pragma unroll
        for (int i = 0; i < 8; ++i) {
            const int e = base + i * 256 + threadIdx.x;
            if (e < NE) {
                const int r = ei[e];
                if (((r >> 4) & 7) == part) {             // line-granular class
                    const int c = ei[NE + e];
                    const int p = atomicAdd(&deg[r], 1);
                    if (p < CAP) slots[r * CAP + p] = c;
                }
            }
        }
        return;
    }

    const int t    = threadIdx.x;
    const int lane = t & 63;
    const int wave = t >> 6;
    const int m16  = lane & 15;
    const int quad = lane >> 4;

    const int row0 = blockIdx.x * TILE_M;
    int gr = row0 + wave * 16 + m16;
    if (gr > NN - 1) gr = NN - 1;          // clamped rows never stored

    // A fragments straight from global x (row gr, cols kc*32+quad*8 .. +7)
    short8 afrag[4];
#pragma unroll
    for (int kc = 0; kc < 4; ++kc) {
        const float4 a0 = *(const float4*)(x + (size_t)gr * 128 + kc * 32 + quad * 8);
        const float4 a1 = *(const float4*)(x + (size_t)gr * 128 + kc * 32 + quad * 8 + 4);
        short8 af;
        af[0] = (short)f2bf(a0.x); af[1] = (short)f2bf(a0.y);
        af[2] = (short)f2bf(a0.z); af[3] = (short)f2bf(a0.w);
        af[4] = (short)f2bf(a1.x); af[5] = (short)f2bf(a1.y);
        af[6] = (short)f2bf(a1.z); af[7] = (short)f2bf(a1.w);
        afrag[kc] = af;
    }

    f32x4 acc[8];
#pragma unroll
    for (int nt = 0; nt < 8; ++nt) acc[nt] = (f32x4){0.f, 0.f, 0.f, 0.f};

#pragma unroll
    for (int kc = 0; kc < 4; ++kc) {
#pragma unroll
        for (int nt = 0; nt < 8; ++nt) {
            const short8 bfrag =
                *(const short8*)(Wbf + (nt * 16 + m16) * 128 + kc * 32 + quad * 8);
            acc[nt] = __builtin_amdgcn_mfma_f32_16x16x32_bf16(
                afrag[kc], bfrag, acc[nt], 0, 0, 0);
        }
    }

    const int rbase = row0 + wave * 16 + quad * 4;
#pragma unroll
    for (int nt = 0; nt < 8; ++nt) {
        const float bias = b[nt * 16 + m16];
#pragma unroll
        for (int r = 0; r < 4; ++r) {
            const int grow = rbase + r;
            if (grow < NN) {
                const float v = acc[nt][r] + bias;
                out[(size_t)grow * 128 + nt * 16 + m16] = v;   // residual base
                hbf[(size_t)grow * 128 + nt * 16 + m16] = f2bf(v);
            }
        }
    }
}

// ---------------- agg: out[n] += sum_{k<deg[n]} h[slots[n][k]] ------------
// One wave per node. Lane = (g,s): g=lane>>4 picks one of 4 concurrent
// edges, s=lane&15 owns 8 cols (16 B uint4 gather). 16 edges/round, 4
// exec-masked loads in flight. Cross-group reduce: 2 shfl_xor steps.
__global__ __launch_bounds__(256) void agg_kernel(
    const int* __restrict__ deg, const int* __restrict__ slots,
    const unsigned short* __restrict__ hbf, float* __restrict__ out)
{
    const int n = (blockIdx.x * 256 + threadIdx.x) >> 6;   // wave-uniform
    if (n >= NN) return;
    const int lane = threadIdx.x & 63;
    const int g = lane >> 4;       // edge group 0..3
    const int s = lane & 15;       // col sub-lane: cols s*8 .. s*8+7

    const int dn_raw = deg[n];
    const int idx    = slots[n * CAP + lane];
    float4 r0, r1;
    if (g == 0) {
        r0 = *(const float4*)(out + (size_t)n * 128 + s * 8);
        r1 = *(const float4*)(out + (size_t)n * 128 + s * 8 + 4);
    }
    const int dn = min(dn_raw, CAP);

    float acc[8];
#pragma unroll
    for (int i = 0; i < 8; ++i) acc[i] = 0.f;

    for (int k = 0; k < dn; k += 16) {
        uint4 p[4];
#pragma unroll
        for (int bb = 0; bb < 4; ++bb) {
            const int e = k + bb * 4 + g;
            const int c = __shfl(idx, e, 64);
            p[bb] = (uint4){0u, 0u, 0u, 0u};
            if (e < dn)
                p[bb] = *(const uint4*)(hbf + (size_t)c * 128 + s * 8);
        }
#pragma unroll
        for (int bb = 0; bb < 4; ++bb) {
            acc[0] += __uint_as_float(p[bb].x << 16);
            acc[1] += __uint_as_float(p[bb].x & 0xffff0000u);
            acc[2] += __uint_as_float(p[bb].y << 16);
            acc[3] += __uint_as_float(p[bb].y & 0xffff0000u);
            acc[4] += __uint_as_float(p[bb].z << 16);
            acc[5] += __uint_as_float(p[bb].z & 0xffff0000u);
            acc[6] += __uint_as_float(p[bb].w << 16);
            acc[7] += __uint_as_float(p[bb].w & 0xffff0000u);
        }
    }

#pragma unroll
    for (int i = 0; i < 8; ++i) acc[i] += __shfl_xor(acc[i], 16, 64);
#pragma unroll
    for (int i = 0; i < 8; ++i) acc[i] += __shfl_xor(acc[i], 32, 64);

    if (g == 0) {
        r0.x += acc[0]; r0.y += acc[1]; r0.z += acc[2]; r0.w += acc[3];
        r1.x += acc[4]; r1.y += acc[5]; r1.z += acc[6]; r1.w += acc[7];
        *(float4*)(out + (size_t)n * 128 + s * 8)     = r0;
        *(float4*)(out + (size_t)n * 128 + s * 8 + 4) = r1;
    }
}

extern "C" void kernel_launch(void* const* d_in, const int* in_sizes, int n_in,
                              void* d_out, int out_size, void* d_ws, size_t ws_size,
                              hipStream_t stream)
{
    const float* x  = (const float*)d_in[0];
    const int*   ei = (const int*)d_in[1];   // int32
    const float* W  = (const float*)d_in[2];
    const float* b  = (const float*)d_in[3];
    float* out = (float*)d_out;

    // Workspace (~25.9 MB): hbf | slots | deg | Wbf
    unsigned short* hbf   = (unsigned short*)d_ws;                // NN*DD bf16
    int*            slots = (int*)(hbf + (size_t)NN * DD);        // NN*CAP
    int*            deg   = slots + (size_t)NN * CAP;             // NN
    unsigned short* Wbf   = (unsigned short*)(deg + NN);          // 128*128 bf16

    prologue<<<64, 256, 0, stream>>>(W, Wbf, deg);

    fused_gemm_scatter<<<NBG + NBS, 256, 0, stream>>>(x, Wbf, b, ei, out, hbf, deg, slots);

    agg_kernel<<<(NN * 64 + 255) / 256, 256, 0, stream>>>(deg, slots, hbf, out);
}